// Round 2
// baseline (187.169 us; speedup 1.0000x reference)
//
#include <hip/hip_runtime.h>

// ws layout (32-bit word offsets). LB arrays are bf16-packed (2 per word):
// LB[j][d] has MP rows, KS bf16 columns (row stride KS), row p holds
// [ L[p][0..M-1], A_mu[p][0], A_mu[p][1], zeros... ]
#define LB0_OFF 0         // 16 * (64*72/2)   = 16*2304  = 36864
#define LB1_OFF 36864     // 16 * (112*136/2) = 16*7616  = 121856
#define LB2_OFF 158720    // 16 * (160*168/2) = 16*13440 = 215040
#define PART_OFF 373760   // 48 partial ldj sums (float)

typedef __attribute__((ext_vector_type(8))) short bf8_t;    // 8 bf16 (4 VGPR)
typedef __attribute__((ext_vector_type(8))) unsigned short us8_t;
typedef __attribute__((ext_vector_type(4))) float f32x4;

__device__ __forceinline__ int tri_i(int p) { return (p * (p + 1)) >> 1; }

__device__ __forceinline__ void tri_decode(int e, int& r, int& c) {
  r = (int)((sqrtf(8.0f * (float)e + 1.0f) - 1.0f) * 0.5f);
  if (tri_i(r + 1) <= e) ++r;
  if (tri_i(r) > e) --r;
  c = e - tri_i(r);
}

// fp32 -> bf16, round-nearest-even
__device__ __forceinline__ unsigned short f2bf(float f) {
  unsigned u = __builtin_bit_cast(unsigned, f);
  u = (u + 0x7FFFu + ((u >> 16) & 1u)) >> 16;
  return (unsigned short)u;
}

// uniform-lane broadcast via v_readlane (no DS pipe, low latency)
__device__ __forceinline__ float blane(float v, int l) {
  return __builtin_bit_cast(float, __builtin_amdgcn_readlane(__builtin_bit_cast(int, v), l));
}
__device__ __forceinline__ float fastrcp(float x) { return __builtin_amdgcn_rcpf(x); }

#define BNT 512   // build_kernel threads (8 waves)

// ---------------------------------------------------------------------------
// Kernel A: per (j,d) Sigma (padded to MP, identity tail), LOOKAHEAD blocked
// raw-Schur Cholesky (bw=16). Per panel pb, the trailing update of panel pb-1
// is split into three pieces scheduled around A(pb)/B(pb):
//   - diag fold: 16x16 block of panel pb, applied in-register by the A-waves
//   - urgent slab (rows [be,mp) x cols [kb,be)): waves 3-7, CONCURRENT with A
//   - lazy bulk (rows,cols >= be): waves 3-7, CONCURRENT with B
// sU/sW are double-buffered by panel parity (B writes parity pb while lazy
// reads parity pb-1). 2 barriers/panel. A/B broadcasts via readlane.
// ---------------------------------------------------------------------------
__global__ __launch_bounds__(BNT) void build_kernel(const float* __restrict__ ts,
                                                    const float* __restrict__ log_tau,
                                                    float* __restrict__ ws)
{
  __shared__ float sS[12880];   // packed lower triangle, padded max mp=160
  __shared__ __attribute__((aligned(16))) float sU[2][160 * 20]; // solved rows, 2 parities
  __shared__ __attribute__((aligned(16))) float sW[2][160 * 20]; // scaled rows, 2 parities
  __shared__ float stj[152];
  __shared__ float sAmu[304];
  __shared__ float sKp[304];
  __shared__ float red[8];

  const int j = blockIdx.x >> 4;
  const int d = blockIdx.x & 15;
  const int m = (j + 1) * 50;
  const int mp    = (j == 0) ? 64      : ((j == 1) ? 112     : 160);
  const int ks    = (j == 0) ? 72      : ((j == 1) ? 136     : 168);
  const int lboff = (j == 0) ? LB0_OFF : ((j == 1) ? LB1_OFF : LB2_OFF);
  const float tpsj = (j == 0) ? 10.0f : ((j == 1) ? 20.0f : 30.0f);
  const int tid  = threadIdx.x;
  const int lane = tid & 63;
  const int wid  = tid >> 6;        // 8 waves

  const float tau = expf(log_tau[d]);
  const float cc = 1.0f / (2.0f * tau * tau);

  for (int i = tid; i < m; i += BNT) stj[i] = ts[i];
  __syncthreads();

  const float k01 = expf(-tpsj * tpsj * cc);
  const float det = 1.0f - k01 * k01;
  const float i00 = 1.0f / det;
  const float i01 = -k01 / det;

  for (int p = tid; p < m; p += BNT) {
    float tp = stj[p];
    float kp0 = expf(-tp * tp * cc);
    float dt = tp - tpsj;
    float kp1 = expf(-dt * dt * cc);
    sKp[p * 2 + 0] = kp0; sKp[p * 2 + 1] = kp1;
    sAmu[p * 2 + 0] = fmaf(kp0, i00, kp1 * i01);
    sAmu[p * 2 + 1] = fmaf(kp0, i01, kp1 * i00);
  }
  __syncthreads();

  // Sigma, padded: rows >= m are identity -> log contrib 0, L tail ignored.
  const int tot = tri_i(mp);
  for (int e = tid; e < tot; e += BNT) {
    int r, q;
    tri_decode(e, r, q);
    float v;
    if (r < m) {
      float dq = stj[r] - stj[q];
      v = expf(-dq * dq * cc)
        - fmaf(sAmu[r * 2], sKp[q * 2], sAmu[r * 2 + 1] * sKp[q * 2 + 1]);
      if (r == q) v += 1e-4f;
    } else {
      v = (r == q) ? 1.0f : 0.0f;
    }
    sS[e] = v;
  }
  __syncthreads();

  // ---- Lookahead blocked raw-Schur Cholesky, bw == 16 ----
  const int npan = mp >> 4;
  const int tr = lane & 15;
  for (int pb = 0; pb < npan; ++pb) {
    const int kb = pb << 4;
    const int be = kb + 16;
    const int rbase = tri_i(kb + tr) + kb;
    float* __restrict__ sUp = sU[pb & 1];
    float* __restrict__ sWp = sW[pb & 1];
    const float* __restrict__ sUq = sU[(pb & 1) ^ 1];
    const float* __restrict__ sWq = sW[(pb & 1) ^ 1];

    // ---- Phase 1: A (waves 0-2, with in-register diag fold)  ||  urgent slab (waves 3-7)
    float rd[16];
    float invd[16];
    if (wid < 3) {
#pragma unroll
      for (int q = 0; q < 16; ++q) rd[q] = sS[rbase + q];
      if (pb > 0) {
        // fold pending C(pb-1) into the diag block rows (register-level)
        float wp[16];
        const float4* wv = (const float4*)&sWq[(kb + tr) * 20];
#pragma unroll
        for (int c4 = 0; c4 < 4; ++c4) *(float4*)&wp[c4 * 4] = wv[c4];
#pragma unroll
        for (int q = 0; q < 16; ++q) {
          const float4* uv = (const float4*)&sUq[(kb + q) * 20];  // wave-uniform
          float u[16];
#pragma unroll
          for (int c4 = 0; c4 < 4; ++c4) *(float4*)&u[c4 * 4] = uv[c4];
          float acc = 0.0f;
#pragma unroll
          for (int s = 0; s < 16; ++s) acc = fmaf(wp[s], u[s], acc);
          rd[q] -= acc;   // junk for q > tr, never read (cross-lane reads use lane>reg)
        }
      }
      // register factor (readlane broadcasts)
#pragma unroll
      for (int kk = 0; kk < 15; ++kk) {
        const float dkk = blane(rd[kk], kk);
        const float ri = fastrcp(dkk);
        invd[kk] = ri;
        const float c = -rd[kk] * ri;
#pragma unroll
        for (int q2 = kk + 1; q2 < 16; ++q2) {
          const float cq2 = blane(rd[kk], q2);
          if (tr > kk && q2 <= tr) rd[q2] = fmaf(c, cq2, rd[q2]);
        }
      }
      invd[15] = fastrcp(blane(rd[15], 15));
    } else if (pb > 0) {
      // urgent slab: C(pb-1) on rows [be,mp) x cols [kb,be)
      const int nel = (mp - be) * 16;
      for (int e = tid - 192; e < nel; e += 320) {
        const int row = be + (e >> 4);
        const int col = kb + (e & 15);
        float wr[16], ur[16];
        const float4* wv = (const float4*)&sWq[row * 20];
        const float4* uv = (const float4*)&sUq[col * 20];
#pragma unroll
        for (int c4 = 0; c4 < 4; ++c4) {
          *(float4*)&wr[c4 * 4] = wv[c4];
          *(float4*)&ur[c4 * 4] = uv[c4];
        }
        const int a = tri_i(row) + col;
        float acc = sS[a];
#pragma unroll
        for (int s = 0; s < 16; ++s) acc = fmaf(-wr[s], ur[s], acc);
        sS[a] = acc;
      }
    }
    __syncthreads();

    // ---- Phase 2: B (waves 0-2)  ||  lazy bulk C(pb-1) (waves 3-7)
    if (wid < 3) {
      if (be < mp) {
        const int i = be + tid;
        if (i < mp) {
          const int base = tri_i(i) + kb;
          float r[16];
#pragma unroll
          for (int t = 0; t < 16; ++t) r[t] = sS[base + t];
#pragma unroll
          for (int kk = 0; kk < 15; ++kk) {
            const float c = r[kk] * invd[kk];
#pragma unroll
            for (int q = kk + 1; q < 16; ++q)
              r[q] = fmaf(-c, blane(rd[kk], q), r[q]);
          }
#pragma unroll
          for (int t = 0; t < 16; ++t) sS[base + t] = r[t];
          float w[16];
#pragma unroll
          for (int t = 0; t < 16; ++t) w[t] = r[t] * invd[t];
          float4* up = (float4*)&sUp[i * 20];
          float4* wp = (float4*)&sWp[i * 20];
#pragma unroll
          for (int c4 = 0; c4 < 4; ++c4) {
            up[c4] = *(float4*)&r[c4 * 4];
            wp[c4] = *(float4*)&w[c4 * 4];
          }
        }
      }
      // factored diag -> sS (rows < be; disjoint from lazy C's rows >= be)
      if (wid == 0 && lane < 16) {
#pragma unroll
        for (int q = 0; q < 16; ++q) if (q <= tr) sS[rbase + q] = rd[q];
      }
    } else if (pb > 0) {
      // lazy bulk: C(pb-1) on rows,cols >= be. 4-row quads, lane = col.
      for (int i0 = be + 4 * (wid - 3); i0 < mp; i0 += 20) {
        float wreg[4][16];
        int rb[4];
#pragma unroll
        for (int r = 0; r < 4; ++r) {
          const float4* wp = (const float4*)&sWq[(i0 + r) * 20];
#pragma unroll
          for (int c4 = 0; c4 < 4; ++c4)
            *(float4*)&wreg[r][c4 * 4] = wp[c4];
          rb[r] = tri_i(i0 + r);
        }
        for (int q0 = be; q0 <= i0 + 3; q0 += 64) {
          const int q = q0 + lane;
          const int qc = (q <= i0 + 3) ? q : (i0 + 3);
          const float4* up = (const float4*)&sUq[qc * 20];
          float u[16];
#pragma unroll
          for (int c4 = 0; c4 < 4; ++c4) *(float4*)&u[c4 * 4] = up[c4];
#pragma unroll
          for (int r = 0; r < 4; ++r) {
            if (q <= i0 + r) {
              const int a = rb[r] + q;
              float acc = sS[a];
#pragma unroll
              for (int t = 0; t < 16; ++t) acc = fmaf(-wreg[r][t], u[t], acc);
              sS[a] = acc;
            }
          }
        }
      }
    }
    __syncthreads();
  }

  // ldj partial: sum 0.5*log(d_p) over real rows; wave reduce, no barrier tree
  float part = 0.0f;
  for (int p = tid; p < m; p += BNT) part += 0.5f * logf(sS[tri_i(p) + p]);
#pragma unroll
  for (int off = 32; off > 0; off >>= 1) part += __shfl_down(part, off);
  if (lane == 0) red[wid] = part;
  __syncthreads();
  if (tid == 0) {
    float s = 0.0f;
#pragma unroll
    for (int w8 = 0; w8 < 8; ++w8) s += red[w8];
    ws[PART_OFF + blockIdx.x] = s;
  }

  // LB (bf16) write: row p, cols k: [L[p][0..m-1], A0[p], A1[p], 0 pad]
  unsigned* LBg = (unsigned*)ws + lboff + d * (mp * (ks >> 1));
  const int nwords = mp * (ks >> 1);
  for (int idx = tid; idx < nwords; idx += BNT) {
    const int p = idx / (ks >> 1);
    const int k0 = (idx - p * (ks >> 1)) * 2;
    unsigned short h[2];
#pragma unroll
    for (int e = 0; e < 2; ++e) {
      const int k = k0 + e;
      float v = 0.0f;
      if (p < m) {
        if (k < m) {
          if (k <= p) {
            const float dq = sS[tri_i(k) + k];
            v = (k == p) ? sqrtf(dq) : sS[tri_i(p) + k] * rsqrtf(dq);
          }
        } else if (k == m)     v = sAmu[p * 2 + 0];
        else if (k == m + 1)   v = sAmu[p * 2 + 1];
      }
      h[e] = f2bf(v);
    }
    LBg[idx] = (unsigned)h[0] | ((unsigned)h[1] << 16);
  }
}

// ---------------------------------------------------------------------------
// Kernel B (MFMA): out[b, p] = sum_k Z'[b,k] * LB[p,k], bf16 16x16x32.
// Z' tile staged in LDS (~11 KB); B-fragments load DIRECTLY from global ws
// (L2-resident, 16B-aligned rows) -> no LB staging, high occupancy.
// ---------------------------------------------------------------------------
template <int M, int MP, int KS, int KT, int TOFF, int OOFF, int LBOFF>
__device__ __forceinline__ void apply_impl(const float* __restrict__ z,
                                           const unsigned* __restrict__ wsu,
                                           float* __restrict__ out,
                                           char* smem, int blk)
{
  constexpr int PT = MP / 16;           // p-tiles
  constexpr int PTH = (PT + 1) / 2;     // p-tiles in first half
  constexpr int CK = KS / 8;            // 8-col chunks per Z row
  const int d   = blk & 15;
  const int bs0 = ((blk >> 4) & 63) * 32;
  const int tid = threadIdx.x;
  const int lane = tid & 63;
  const int wv   = tid >> 6;            // 4 waves
  const int rt   = wv & 1;              // row-tile (16 rows each)
  const int ph   = wv >> 1;             // p-half

  unsigned short* Zs = (unsigned short*)smem;   // 32 x KS bf16

  // stage Z' tile (bf16): row r, cols k -> z[row][TOFF+k] | zf | zl | 0
  for (int idx = tid; idx < 32 * CK; idx += 256) {
    const int r = idx / CK;
    const int k0 = (idx - r * CK) * 8;
    const float* zr = z + (size_t)((bs0 + r) * 16 + d) * 302;
    us8_t v;
    if (k0 + 8 <= M) {
#pragma unroll
      for (int t = 0; t < 4; ++t) {
        const float2 f = *(const float2*)(zr + TOFF + k0 + 2 * t);
        v[2 * t]     = f2bf(f.x);
        v[2 * t + 1] = f2bf(f.y);
      }
    } else {
#pragma unroll
      for (int e = 0; e < 8; ++e) {
        const int k = k0 + e;
        float f;
        if (k < M)           f = zr[TOFF + k];
        else if (k == M)     f = zr[0];
        else if (k == M + 1) f = zr[1];
        else                 f = 0.0f;
        v[e] = f2bf(f);
      }
    }
    *(us8_t*)&Zs[r * KS + k0] = v;
  }

  // zf / zl pass-through columns (exact fp32)
  if (tid < 64) {
    const int r = tid >> 1;
    const int which = tid & 1;
    const float* zr = z + (size_t)((bs0 + r) * 16 + d) * 302;
    out[(size_t)((bs0 + r) * 16 + d) * 306 + OOFF + (which ? (M + 1) : 0)] = zr[which];
  }
  __syncthreads();

  // A fragments: 16 rows (lane&15) x 32k per kt, register-resident
  bf8_t afr[KT];
  {
    const int row = rt * 16 + (lane & 15);
    const int koff = (lane >> 4) * 8;
#pragma unroll
    for (int kt = 0; kt < KT; ++kt)
      afr[kt] = *(const bf8_t*)&Zs[row * KS + kt * 32 + koff];
  }

  const unsigned short* LBd = (const unsigned short*)(wsu + LBOFF + d * (MP * (KS / 2)));
  const int pt0 = ph * PTH;
  const int pt1 = (ph == 0) ? PTH : PT;
  for (int pt = pt0; pt < pt1; ++pt) {
    const int p = pt * 16 + (lane & 15);
    const unsigned short* bb = &LBd[p * KS + (lane >> 4) * 8];
    f32x4 acc = {0.0f, 0.0f, 0.0f, 0.0f};
#pragma unroll
    for (int kt = 0; kt < KT; ++kt) {
      const bf8_t bfr = *(const bf8_t*)&bb[kt * 32];   // 16B global load (L2)
      acc = __builtin_amdgcn_mfma_f32_16x16x32_bf16(afr[kt], bfr, acc, 0, 0, 0);
    }
    if (p < M) {
      const int rbase = bs0 + rt * 16 + (lane >> 4) * 4;
#pragma unroll
      for (int e = 0; e < 4; ++e)
        out[(size_t)((rbase + e) * 16 + d) * 306 + OOFF + 1 + p] = acc[e];
    }
  }
}

__global__ __launch_bounds__(256) void apply_kernel(const float* __restrict__ z,
                                                    const unsigned* __restrict__ wsu,
                                                    float* __restrict__ out)
{
  __shared__ __attribute__((aligned(16))) char smem[10752]; // 32*168*2
  const int bid = blockIdx.x;
  if (bid < 1024)      apply_impl<150, 160, 168, 5, 152, 154, LB2_OFF>(z, wsu, out, smem, bid);
  else if (bid < 2048) apply_impl<100, 112, 136, 4,  52,  52, LB1_OFF>(z, wsu, out, smem, bid - 1024);
  else                 apply_impl< 50,  64,  72, 2,   2,   0, LB0_OFF>(z, wsu, out, smem, bid - 2048);
}

// ---------------------------------------------------------------------------
// Kernel C: ldj = sldj_in + sum of 48 partials
// ---------------------------------------------------------------------------
__global__ void finalize_kernel(const float* __restrict__ ws_part,
                                const float* __restrict__ sldj,
                                float* __restrict__ out, int last)
{
  if (threadIdx.x == 0) {
    float s = sldj[0];
    for (int i = 0; i < 48; ++i) s += ws_part[i];
    out[last] = s;
  }
}

extern "C" void kernel_launch(void* const* d_in, const int* in_sizes, int n_in,
                              void* d_out, int out_size, void* d_ws, size_t ws_size,
                              hipStream_t stream)
{
  const float* z       = (const float*)d_in[0];  // (16,128,16,302)
  const float* ts      = (const float*)d_in[1];  // (3,50) flat
  const float* log_tau = (const float*)d_in[2];  // (16,)
  const float* sldj    = (const float*)d_in[3];  // scalar
  float* out = (float*)d_out;                    // 16*128*16*306 + 1
  float* ws  = (float*)d_ws;

  hipLaunchKernelGGL(build_kernel, dim3(48), dim3(BNT), 0, stream, ts, log_tau, ws);
  hipLaunchKernelGGL(apply_kernel, dim3(3072), dim3(256), 0, stream,
                     z, (const unsigned*)ws, out);
  hipLaunchKernelGGL(finalize_kernel, dim3(1), dim3(64), 0, stream,
                     ws + PART_OFF, sldj, out, out_size - 1);
}

// Round 4
// 175.993 us; speedup vs baseline: 1.0635x; 1.0635x over previous
//
#include <hip/hip_runtime.h>

// ws layout (32-bit word offsets). LB arrays are bf16-packed (2 per word):
// LB[j][d] has MP rows, KS bf16 columns (row stride KS), row p holds
// [ L[p][0..M-1], A_mu[p][0], A_mu[p][1], zeros... ]
#define LB0_OFF 0         // 16 * (64*72/2)   = 16*2304  = 36864
#define LB1_OFF 36864     // 16 * (112*136/2) = 16*7616  = 121856
#define LB2_OFF 158720    // 16 * (160*168/2) = 16*13440 = 215040
#define PART_OFF 373760   // 48 partial ldj sums (float)

typedef __attribute__((ext_vector_type(8))) short bf8_t;    // 8 bf16 (4 VGPR)
typedef __attribute__((ext_vector_type(8))) unsigned short us8_t;
typedef __attribute__((ext_vector_type(4))) float f32x4;

__device__ __forceinline__ int tri_i(int p) { return (p * (p + 1)) >> 1; }

// Collision-free 16B-aligned packed-triangle layout: row p is padded to
// 4*ceil((p+1)/4) floats. Cumulative start (closed form, verified):
//   roff(p) = 4*(T+1)*(2T+r),  T = p>>2, r = p&3
// Rows are DISJOINT (unlike (tri+3)&~3, which aliased row p's tail with
// row p+1's head and caused the R3 NaN). Total for MP=160: 13120 floats.
__device__ __forceinline__ int roff(int p) {
  const int T = p >> 2, r = p & 3;
  return ((T + 1) * (2 * T + r)) << 2;
}

__device__ __forceinline__ void tri_decode(int e, int& r, int& c) {
  r = (int)((sqrtf(8.0f * (float)e + 1.0f) - 1.0f) * 0.5f);
  if (tri_i(r + 1) <= e) ++r;
  if (tri_i(r) > e) --r;
  c = e - tri_i(r);
}

// fp32 -> bf16, round-nearest-even
__device__ __forceinline__ unsigned short f2bf(float f) {
  unsigned u = __builtin_bit_cast(unsigned, f);
  u = (u + 0x7FFFu + ((u >> 16) & 1u)) >> 16;
  return (unsigned short)u;
}

// uniform-lane broadcast via v_readlane (no DS pipe, low latency)
__device__ __forceinline__ float blane(float v, int l) {
  return __builtin_bit_cast(float, __builtin_amdgcn_readlane(__builtin_bit_cast(int, v), l));
}
__device__ __forceinline__ float fastrcp(float x) { return __builtin_amdgcn_rcpf(x); }

#define BNT 512   // build_kernel threads (8 waves)

// ---------------------------------------------------------------------------
// Kernel A (R1 structure, j-templated): per (j,d) Sigma (padded to MP,
// identity tail), blocked raw-Schur Cholesky (bw=16):
//  - phase A (diag factor) replicated in-register in waves 0..2 via readlane
//  - phase B row-solve (1 thread/row), b128 row loads/stores (aligned rows)
//  - phase C trailing update on all 8 waves (4-row quads, lane = col)
//  - 2 barriers/panel; ldj via wave shfl reduce
// Compile-time M/MP/KS turn the LB-write division into a magic-mul and make
// all trip counts constant.
// ---------------------------------------------------------------------------
template <int J>
__device__ __forceinline__ void build_impl(int d,
                                           const float* __restrict__ ts,
                                           const float* __restrict__ log_tau,
                                           float* __restrict__ ws,
                                           float* sS, float* sU, float* sW,
                                           float* stj, float* sAmu, float* sKp,
                                           float* red)
{
  constexpr int M  = (J + 1) * 50;
  constexpr int MP = (J == 0) ? 64 : ((J == 1) ? 112 : 160);
  constexpr int KS = (J == 0) ? 72 : ((J == 1) ? 136 : 168);
  constexpr int LBOFF = (J == 0) ? LB0_OFF : ((J == 1) ? LB1_OFF : LB2_OFF);
  constexpr float TPSJ = (J == 0) ? 10.0f : ((J == 1) ? 20.0f : 30.0f);
  constexpr int KW = KS / 2;
  constexpr int TOT = (MP * (MP + 1)) / 2;
  constexpr int NPAN = MP / 16;

  const int tid  = threadIdx.x;
  const int lane = tid & 63;
  const int wid  = tid >> 6;        // 8 waves

  const float tau = expf(log_tau[d]);
  const float cc = 1.0f / (2.0f * tau * tau);

  for (int i = tid; i < M; i += BNT) stj[i] = ts[i];
  __syncthreads();

  const float k01 = expf(-TPSJ * TPSJ * cc);
  const float det = 1.0f - k01 * k01;
  const float i00 = 1.0f / det;
  const float i01 = -k01 / det;

  for (int p = tid; p < M; p += BNT) {
    float tp = stj[p];
    float kp0 = expf(-tp * tp * cc);
    float dt = tp - TPSJ;
    float kp1 = expf(-dt * dt * cc);
    sKp[p * 2 + 0] = kp0; sKp[p * 2 + 1] = kp1;
    sAmu[p * 2 + 0] = fmaf(kp0, i00, kp1 * i01);
    sAmu[p * 2 + 1] = fmaf(kp0, i01, kp1 * i00);
  }
  __syncthreads();

  // Sigma, padded: rows >= M are identity -> log contrib 0, L tail ignored.
  for (int e = tid; e < TOT; e += BNT) {
    int r, q;
    tri_decode(e, r, q);
    float v;
    if (r < M) {
      float dq = stj[r] - stj[q];
      v = expf(-dq * dq * cc)
        - fmaf(sAmu[r * 2], sKp[q * 2], sAmu[r * 2 + 1] * sKp[q * 2 + 1]);
      if (r == q) v += 1e-4f;
    } else {
      v = (r == q) ? 1.0f : 0.0f;
    }
    sS[roff(r) + q] = v;
  }
  __syncthreads();

  // ---- Blocked raw-Schur Cholesky, bw == 16 always ----
  const int tr = lane & 15;
#pragma unroll 1
  for (int pb = 0; pb < NPAN; ++pb) {
    const int kb = pb << 4;
    const int be = kb + 16;
    const int rbase = roff(kb + tr) + kb;   // 16B-aligned

    // phase A: diag block factor in registers, replicated in waves 0..2.
    // b128 reads may cover pad/junk for q > tr — never consumed (cross-lane
    // access blane(rd[kk], q2) reads lane q2, whose cols <= q2 are valid).
    float rd[16];
    float invd[16];
    if (wid < 3) {
      const float4* rp = (const float4*)&sS[rbase];
#pragma unroll
      for (int c4 = 0; c4 < 4; ++c4) *(float4*)&rd[c4 * 4] = rp[c4];
#pragma unroll
      for (int kk = 0; kk < 15; ++kk) {
        const float dkk = blane(rd[kk], kk);
        const float ri = fastrcp(dkk);
        invd[kk] = ri;
        const float c = -rd[kk] * ri;
#pragma unroll
        for (int q2 = kk + 1; q2 < 16; ++q2) {
          const float cq2 = blane(rd[kk], q2);
          if (tr > kk && q2 <= tr) rd[q2] = fmaf(c, cq2, rd[q2]);
        }
      }
      invd[15] = fastrcp(blane(rd[15], 15));
    }

    // phase B (no barrier after A: same waves): row-solve, 1 thread per row.
    // Rows i >= be have cols kb..kb+15 all valid (kb+15 < i+1) -> full b128.
    if (be < MP) {
      const int i = be + tid;
      if (i < MP) {
        const int base = roff(i) + kb;      // 16B-aligned
        float r[16];
        const float4* rp = (const float4*)&sS[base];
#pragma unroll
        for (int c4 = 0; c4 < 4; ++c4) *(float4*)&r[c4 * 4] = rp[c4];
#pragma unroll
        for (int kk = 0; kk < 15; ++kk) {
          const float c = r[kk] * invd[kk];
#pragma unroll
          for (int q = kk + 1; q < 16; ++q)
            r[q] = fmaf(-c, blane(rd[kk], q), r[q]);
        }
        float4* sp = (float4*)&sS[base];
#pragma unroll
        for (int c4 = 0; c4 < 4; ++c4) sp[c4] = *(float4*)&r[c4 * 4];
        float w[16];
#pragma unroll
        for (int t = 0; t < 16; ++t) w[t] = r[t] * invd[t];
        float4* up = (float4*)&sU[i * 20];
        float4* wp = (float4*)&sW[i * 20];
#pragma unroll
        for (int c4 = 0; c4 < 4; ++c4) {
          up[c4] = *(float4*)&r[c4 * 4];
          wp[c4] = *(float4*)&w[c4 * 4];
        }
      }
    }
    __syncthreads();

    // factored diag -> sS (predicated: q > tr is beyond row's valid cols)
    if (wid == 0 && lane < 16) {
#pragma unroll
      for (int q = 0; q < 16; ++q) if (q <= tr) sS[rbase + q] = rd[q];
    }

    // phase C: trailing update. wave = 4-row quad, lane = col (stride 64).
    if (be < MP) {
      for (int i0 = be + 4 * wid; i0 < MP; i0 += 32) {
        float wreg[4][16];
        int rb[4];
#pragma unroll
        for (int r = 0; r < 4; ++r) {
          const float4* wp = (const float4*)&sW[(i0 + r) * 20];
#pragma unroll
          for (int c4 = 0; c4 < 4; ++c4)
            *(float4*)&wreg[r][c4 * 4] = wp[c4];
          rb[r] = roff(i0 + r);
        }
        for (int q0 = be; q0 <= i0 + 3; q0 += 64) {
          const int q = q0 + lane;
          const int qc = (q <= i0 + 3) ? q : (i0 + 3);
          const float4* up = (const float4*)&sU[qc * 20];
          float u[16];
#pragma unroll
          for (int c4 = 0; c4 < 4; ++c4) *(float4*)&u[c4 * 4] = up[c4];
#pragma unroll
          for (int r = 0; r < 4; ++r) {
            if (q <= i0 + r) {
              const int a = rb[r] + q;
              float acc = sS[a];
#pragma unroll
              for (int t = 0; t < 16; ++t) acc = fmaf(-wreg[r][t], u[t], acc);
              sS[a] = acc;
            }
          }
        }
      }
    }
    __syncthreads();
  }

  // ldj partial: sum 0.5*log(d_p) over real rows; wave reduce, no barrier tree
  float part = 0.0f;
  for (int p = tid; p < M; p += BNT) part += 0.5f * logf(sS[roff(p) + p]);
#pragma unroll
  for (int off = 32; off > 0; off >>= 1) part += __shfl_down(part, off);
  if (lane == 0) red[wid] = part;
  __syncthreads();
  if (tid == 0) {
    float s = 0.0f;
#pragma unroll
    for (int w8 = 0; w8 < 8; ++w8) s += red[w8];
    ws[PART_OFF + J * 16 + d] = s;
  }

  // LB (bf16) write: row p, cols k: [L[p][0..M-1], A0[p], A1[p], 0 pad]
  // KW is constexpr -> idx/KW compiles to a magic-mul, not v_rcp division.
  unsigned* LBg = (unsigned*)ws + LBOFF + d * (MP * KW);
  constexpr int NWORDS = MP * KW;
  for (int idx = tid; idx < NWORDS; idx += BNT) {
    const int p = idx / KW;
    const int k0 = (idx - p * KW) * 2;
    unsigned short h[2];
#pragma unroll
    for (int e = 0; e < 2; ++e) {
      const int k = k0 + e;
      float v = 0.0f;
      if (p < M) {
        if (k < M) {
          if (k <= p) {
            const float dq = sS[roff(k) + k];
            v = (k == p) ? sqrtf(dq) : sS[roff(p) + k] * rsqrtf(dq);
          }
        } else if (k == M)     v = sAmu[p * 2 + 0];
        else if (k == M + 1)   v = sAmu[p * 2 + 1];
      }
      h[e] = f2bf(v);
    }
    LBg[idx] = (unsigned)h[0] | ((unsigned)h[1] << 16);
  }
}

__global__ __launch_bounds__(BNT) void build_kernel(const float* __restrict__ ts,
                                                    const float* __restrict__ log_tau,
                                                    float* __restrict__ ws)
{
  __shared__ float sS[13120];   // aligned packed lower triangle (mp=160)
  __shared__ __attribute__((aligned(16))) float sU[160 * 20]; // solved panel rows
  __shared__ __attribute__((aligned(16))) float sW[160 * 20]; // scaled panel rows
  __shared__ float stj[152];
  __shared__ float sAmu[304];
  __shared__ float sKp[304];
  __shared__ float red[8];

  const int j = blockIdx.x >> 4;
  const int d = blockIdx.x & 15;
  if (j == 0)      build_impl<0>(d, ts, log_tau, ws, sS, sU, sW, stj, sAmu, sKp, red);
  else if (j == 1) build_impl<1>(d, ts, log_tau, ws, sS, sU, sW, stj, sAmu, sKp, red);
  else             build_impl<2>(d, ts, log_tau, ws, sS, sU, sW, stj, sAmu, sKp, red);
}

// ---------------------------------------------------------------------------
// Kernel B (MFMA): out[b, p] = sum_k Z'[b,k] * LB[p,k], bf16 16x16x32.
// Z' tile staged in LDS (~11 KB); B-fragments load DIRECTLY from global ws
// (L2-resident, 16B-aligned rows) -> no LB staging, high occupancy.
// Finalize (ldj sum) fused into block 3071 (a j=0 block, least loaded).
// ---------------------------------------------------------------------------
template <int M, int MP, int KS, int KT, int TOFF, int OOFF, int LBOFF>
__device__ __forceinline__ void apply_impl(const float* __restrict__ z,
                                           const unsigned* __restrict__ wsu,
                                           float* __restrict__ out,
                                           char* smem, int blk)
{
  constexpr int PT = MP / 16;           // p-tiles
  constexpr int PTH = (PT + 1) / 2;     // p-tiles in first half
  constexpr int CK = KS / 8;            // 8-col chunks per Z row
  const int d   = blk & 15;
  const int bs0 = ((blk >> 4) & 63) * 32;
  const int tid = threadIdx.x;
  const int lane = tid & 63;
  const int wv   = tid >> 6;            // 4 waves
  const int rt   = wv & 1;              // row-tile (16 rows each)
  const int ph   = wv >> 1;             // p-half

  unsigned short* Zs = (unsigned short*)smem;   // 32 x KS bf16

  // stage Z' tile (bf16): row r, cols k -> z[row][TOFF+k] | zf | zl | 0
  for (int idx = tid; idx < 32 * CK; idx += 256) {
    const int r = idx / CK;
    const int k0 = (idx - r * CK) * 8;
    const float* zr = z + (size_t)((bs0 + r) * 16 + d) * 302;
    us8_t v;
    if (k0 + 8 <= M) {
#pragma unroll
      for (int t = 0; t < 4; ++t) {
        const float2 f = *(const float2*)(zr + TOFF + k0 + 2 * t);
        v[2 * t]     = f2bf(f.x);
        v[2 * t + 1] = f2bf(f.y);
      }
    } else {
#pragma unroll
      for (int e = 0; e < 8; ++e) {
        const int k = k0 + e;
        float f;
        if (k < M)           f = zr[TOFF + k];
        else if (k == M)     f = zr[0];
        else if (k == M + 1) f = zr[1];
        else                 f = 0.0f;
        v[e] = f2bf(f);
      }
    }
    *(us8_t*)&Zs[r * KS + k0] = v;
  }

  // zf / zl pass-through columns (exact fp32)
  if (tid < 64) {
    const int r = tid >> 1;
    const int which = tid & 1;
    const float* zr = z + (size_t)((bs0 + r) * 16 + d) * 302;
    out[(size_t)((bs0 + r) * 16 + d) * 306 + OOFF + (which ? (M + 1) : 0)] = zr[which];
  }
  __syncthreads();

  // A fragments: 16 rows (lane&15) x 32k per kt, register-resident
  bf8_t afr[KT];
  {
    const int row = rt * 16 + (lane & 15);
    const int koff = (lane >> 4) * 8;
#pragma unroll
    for (int kt = 0; kt < KT; ++kt)
      afr[kt] = *(const bf8_t*)&Zs[row * KS + kt * 32 + koff];
  }

  const unsigned short* LBd = (const unsigned short*)(wsu + LBOFF + d * (MP * (KS / 2)));
  const int pt0 = ph * PTH;
  const int pt1 = (ph == 0) ? PTH : PT;
  for (int pt = pt0; pt < pt1; ++pt) {
    const int p = pt * 16 + (lane & 15);
    const unsigned short* bb = &LBd[p * KS + (lane >> 4) * 8];
    f32x4 acc = {0.0f, 0.0f, 0.0f, 0.0f};
#pragma unroll
    for (int kt = 0; kt < KT; ++kt) {
      const bf8_t bfr = *(const bf8_t*)&bb[kt * 32];   // 16B global load (L2)
      acc = __builtin_amdgcn_mfma_f32_16x16x32_bf16(afr[kt], bfr, acc, 0, 0, 0);
    }
    if (p < M) {
      const int rbase = bs0 + rt * 16 + (lane >> 4) * 4;
#pragma unroll
      for (int e = 0; e < 4; ++e)
        out[(size_t)((rbase + e) * 16 + d) * 306 + OOFF + 1 + p] = acc[e];
    }
  }
}

__global__ __launch_bounds__(256) void apply_kernel(const float* __restrict__ z,
                                                    const unsigned* __restrict__ wsu,
                                                    float* __restrict__ out,
                                                    const float* __restrict__ part,
                                                    const float* __restrict__ sldj,
                                                    int last)
{
  __shared__ __attribute__((aligned(16))) char smem[10752]; // 32*168*2
  const int bid = blockIdx.x;
  if (bid == 3071 && threadIdx.x == 0) {
    // fused finalize: ldj = sldj_in + sum of 48 build partials
    float s = sldj[0];
#pragma unroll
    for (int i = 0; i < 48; ++i) s += part[i];
    out[last] = s;
  }
  if (bid < 1024)      apply_impl<150, 160, 168, 5, 152, 154, LB2_OFF>(z, wsu, out, smem, bid);
  else if (bid < 2048) apply_impl<100, 112, 136, 4,  52,  52, LB1_OFF>(z, wsu, out, smem, bid - 1024);
  else                 apply_impl< 50,  64,  72, 2,   2,   0, LB0_OFF>(z, wsu, out, smem, bid - 2048);
}

extern "C" void kernel_launch(void* const* d_in, const int* in_sizes, int n_in,
                              void* d_out, int out_size, void* d_ws, size_t ws_size,
                              hipStream_t stream)
{
  const float* z       = (const float*)d_in[0];  // (16,128,16,302)
  const float* ts      = (const float*)d_in[1];  // (3,50) flat
  const float* log_tau = (const float*)d_in[2];  // (16,)
  const float* sldj    = (const float*)d_in[3];  // scalar
  float* out = (float*)d_out;                    // 16*128*16*306 + 1
  float* ws  = (float*)d_ws;

  hipLaunchKernelGGL(build_kernel, dim3(48), dim3(BNT), 0, stream, ts, log_tau, ws);
  hipLaunchKernelGGL(apply_kernel, dim3(3072), dim3(256), 0, stream,
                     z, (const unsigned*)ws, out,
                     ws + PART_OFF, sldj, out_size - 1);
}

// Round 5
// 173.590 us; speedup vs baseline: 1.0782x; 1.0138x over previous
//
#include <hip/hip_runtime.h>

// ws layout (32-bit word offsets). LB arrays are bf16-packed (2 per word):
// LB[j][d] has MP rows, KS bf16 columns (row stride KS), row p holds
// [ L[p][0..M-1], A_mu[p][0], A_mu[p][1], zeros... ]
#define LB0_OFF 0         // 16 * (64*72/2)   = 16*2304  = 36864
#define LB1_OFF 36864     // 16 * (112*136/2) = 16*7616  = 121856
#define LB2_OFF 158720    // 16 * (160*168/2) = 16*13440 = 215040
#define PART_OFF 373760   // 48 partial ldj sums (float)

typedef __attribute__((ext_vector_type(8))) short bf8_t;    // 8 bf16 (4 VGPR)
typedef __attribute__((ext_vector_type(8))) unsigned short us8_t;
typedef __attribute__((ext_vector_type(4))) float f32x4;

__device__ __forceinline__ int tri_i(int p) { return (p * (p + 1)) >> 1; }

// Collision-free 16B-aligned packed-triangle layout: row p is padded to
// 4*ceil((p+1)/4) floats. Cumulative start (closed form, verified):
//   roff(p) = 4*(T+1)*(2T+r),  T = p>>2, r = p&3
__device__ __forceinline__ int roff(int p) {
  const int T = p >> 2, r = p & 3;
  return ((T + 1) * (2 * T + r)) << 2;
}

__device__ __forceinline__ void tri_decode(int e, int& r, int& c) {
  r = (int)((sqrtf(8.0f * (float)e + 1.0f) - 1.0f) * 0.5f);
  if (tri_i(r + 1) <= e) ++r;
  if (tri_i(r) > e) --r;
  c = e - tri_i(r);
}

// fp32 -> bf16, round-nearest-even
__device__ __forceinline__ unsigned short f2bf(float f) {
  unsigned u = __builtin_bit_cast(unsigned, f);
  u = (u + 0x7FFFu + ((u >> 16) & 1u)) >> 16;
  return (unsigned short)u;
}

// uniform-lane broadcast via v_readlane (no DS pipe, low latency)
__device__ __forceinline__ float blane(float v, int l) {
  return __builtin_bit_cast(float, __builtin_amdgcn_readlane(__builtin_bit_cast(int, v), l));
}
__device__ __forceinline__ float fastrcp(float x) { return __builtin_amdgcn_rcpf(x); }

#define BNT 512   // build_kernel threads (8 waves)

// ---------------------------------------------------------------------------
// Kernel A (FROZEN from R4, known-good): per (j,d) Sigma (padded to MP,
// identity tail), blocked raw-Schur Cholesky (bw=16).
// ---------------------------------------------------------------------------
template <int J>
__device__ __forceinline__ void build_impl(int d,
                                           const float* __restrict__ ts,
                                           const float* __restrict__ log_tau,
                                           float* __restrict__ ws,
                                           float* sS, float* sU, float* sW,
                                           float* stj, float* sAmu, float* sKp,
                                           float* red)
{
  constexpr int M  = (J + 1) * 50;
  constexpr int MP = (J == 0) ? 64 : ((J == 1) ? 112 : 160);
  constexpr int KS = (J == 0) ? 72 : ((J == 1) ? 136 : 168);
  constexpr int LBOFF = (J == 0) ? LB0_OFF : ((J == 1) ? LB1_OFF : LB2_OFF);
  constexpr float TPSJ = (J == 0) ? 10.0f : ((J == 1) ? 20.0f : 30.0f);
  constexpr int KW = KS / 2;
  constexpr int TOT = (MP * (MP + 1)) / 2;
  constexpr int NPAN = MP / 16;

  const int tid  = threadIdx.x;
  const int lane = tid & 63;
  const int wid  = tid >> 6;        // 8 waves

  const float tau = expf(log_tau[d]);
  const float cc = 1.0f / (2.0f * tau * tau);

  for (int i = tid; i < M; i += BNT) stj[i] = ts[i];
  __syncthreads();

  const float k01 = expf(-TPSJ * TPSJ * cc);
  const float det = 1.0f - k01 * k01;
  const float i00 = 1.0f / det;
  const float i01 = -k01 / det;

  for (int p = tid; p < M; p += BNT) {
    float tp = stj[p];
    float kp0 = expf(-tp * tp * cc);
    float dt = tp - TPSJ;
    float kp1 = expf(-dt * dt * cc);
    sKp[p * 2 + 0] = kp0; sKp[p * 2 + 1] = kp1;
    sAmu[p * 2 + 0] = fmaf(kp0, i00, kp1 * i01);
    sAmu[p * 2 + 1] = fmaf(kp0, i01, kp1 * i00);
  }
  __syncthreads();

  // Sigma, padded: rows >= M are identity -> log contrib 0, L tail ignored.
  for (int e = tid; e < TOT; e += BNT) {
    int r, q;
    tri_decode(e, r, q);
    float v;
    if (r < M) {
      float dq = stj[r] - stj[q];
      v = expf(-dq * dq * cc)
        - fmaf(sAmu[r * 2], sKp[q * 2], sAmu[r * 2 + 1] * sKp[q * 2 + 1]);
      if (r == q) v += 1e-4f;
    } else {
      v = (r == q) ? 1.0f : 0.0f;
    }
    sS[roff(r) + q] = v;
  }
  __syncthreads();

  // ---- Blocked raw-Schur Cholesky, bw == 16 always ----
  const int tr = lane & 15;
#pragma unroll 1
  for (int pb = 0; pb < NPAN; ++pb) {
    const int kb = pb << 4;
    const int be = kb + 16;
    const int rbase = roff(kb + tr) + kb;   // 16B-aligned

    // phase A: diag block factor in registers, replicated in waves 0..2.
    float rd[16];
    float invd[16];
    if (wid < 3) {
      const float4* rp = (const float4*)&sS[rbase];
#pragma unroll
      for (int c4 = 0; c4 < 4; ++c4) *(float4*)&rd[c4 * 4] = rp[c4];
#pragma unroll
      for (int kk = 0; kk < 15; ++kk) {
        const float dkk = blane(rd[kk], kk);
        const float ri = fastrcp(dkk);
        invd[kk] = ri;
        const float c = -rd[kk] * ri;
#pragma unroll
        for (int q2 = kk + 1; q2 < 16; ++q2) {
          const float cq2 = blane(rd[kk], q2);
          if (tr > kk && q2 <= tr) rd[q2] = fmaf(c, cq2, rd[q2]);
        }
      }
      invd[15] = fastrcp(blane(rd[15], 15));
    }

    // phase B (no barrier after A: same waves): row-solve, 1 thread per row.
    if (be < MP) {
      const int i = be + tid;
      if (i < MP) {
        const int base = roff(i) + kb;      // 16B-aligned
        float r[16];
        const float4* rp = (const float4*)&sS[base];
#pragma unroll
        for (int c4 = 0; c4 < 4; ++c4) *(float4*)&r[c4 * 4] = rp[c4];
#pragma unroll
        for (int kk = 0; kk < 15; ++kk) {
          const float c = r[kk] * invd[kk];
#pragma unroll
          for (int q = kk + 1; q < 16; ++q)
            r[q] = fmaf(-c, blane(rd[kk], q), r[q]);
        }
        float4* sp = (float4*)&sS[base];
#pragma unroll
        for (int c4 = 0; c4 < 4; ++c4) sp[c4] = *(float4*)&r[c4 * 4];
        float w[16];
#pragma unroll
        for (int t = 0; t < 16; ++t) w[t] = r[t] * invd[t];
        float4* up = (float4*)&sU[i * 20];
        float4* wp = (float4*)&sW[i * 20];
#pragma unroll
        for (int c4 = 0; c4 < 4; ++c4) {
          up[c4] = *(float4*)&r[c4 * 4];
          wp[c4] = *(float4*)&w[c4 * 4];
        }
      }
    }
    __syncthreads();

    // factored diag -> sS (predicated: q > tr is beyond row's valid cols)
    if (wid == 0 && lane < 16) {
#pragma unroll
      for (int q = 0; q < 16; ++q) if (q <= tr) sS[rbase + q] = rd[q];
    }

    // phase C: trailing update. wave = 4-row quad, lane = col (stride 64).
    if (be < MP) {
      for (int i0 = be + 4 * wid; i0 < MP; i0 += 32) {
        float wreg[4][16];
        int rb[4];
#pragma unroll
        for (int r = 0; r < 4; ++r) {
          const float4* wp = (const float4*)&sW[(i0 + r) * 20];
#pragma unroll
          for (int c4 = 0; c4 < 4; ++c4)
            *(float4*)&wreg[r][c4 * 4] = wp[c4];
          rb[r] = roff(i0 + r);
        }
        for (int q0 = be; q0 <= i0 + 3; q0 += 64) {
          const int q = q0 + lane;
          const int qc = (q <= i0 + 3) ? q : (i0 + 3);
          const float4* up = (const float4*)&sU[qc * 20];
          float u[16];
#pragma unroll
          for (int c4 = 0; c4 < 4; ++c4) *(float4*)&u[c4 * 4] = up[c4];
#pragma unroll
          for (int r = 0; r < 4; ++r) {
            if (q <= i0 + r) {
              const int a = rb[r] + q;
              float acc = sS[a];
#pragma unroll
              for (int t = 0; t < 16; ++t) acc = fmaf(-wreg[r][t], u[t], acc);
              sS[a] = acc;
            }
          }
        }
      }
    }
    __syncthreads();
  }

  // ldj partial: sum 0.5*log(d_p) over real rows; wave reduce
  float part = 0.0f;
  for (int p = tid; p < M; p += BNT) part += 0.5f * logf(sS[roff(p) + p]);
#pragma unroll
  for (int off = 32; off > 0; off >>= 1) part += __shfl_down(part, off);
  if (lane == 0) red[wid] = part;
  __syncthreads();
  if (tid == 0) {
    float s = 0.0f;
#pragma unroll
    for (int w8 = 0; w8 < 8; ++w8) s += red[w8];
    ws[PART_OFF + J * 16 + d] = s;
  }

  // LB (bf16) write: row p, cols k: [L[p][0..M-1], A0[p], A1[p], 0 pad]
  unsigned* LBg = (unsigned*)ws + LBOFF + d * (MP * KW);
  constexpr int NWORDS = MP * KW;
  for (int idx = tid; idx < NWORDS; idx += BNT) {
    const int p = idx / KW;
    const int k0 = (idx - p * KW) * 2;
    unsigned short h[2];
#pragma unroll
    for (int e = 0; e < 2; ++e) {
      const int k = k0 + e;
      float v = 0.0f;
      if (p < M) {
        if (k < M) {
          if (k <= p) {
            const float dq = sS[roff(k) + k];
            v = (k == p) ? sqrtf(dq) : sS[roff(p) + k] * rsqrtf(dq);
          }
        } else if (k == M)     v = sAmu[p * 2 + 0];
        else if (k == M + 1)   v = sAmu[p * 2 + 1];
      }
      h[e] = f2bf(v);
    }
    LBg[idx] = (unsigned)h[0] | ((unsigned)h[1] << 16);
  }
}

__global__ __launch_bounds__(BNT) void build_kernel(const float* __restrict__ ts,
                                                    const float* __restrict__ log_tau,
                                                    float* __restrict__ ws)
{
  __shared__ float sS[13120];   // aligned packed lower triangle (mp=160)
  __shared__ __attribute__((aligned(16))) float sU[160 * 20]; // solved panel rows
  __shared__ __attribute__((aligned(16))) float sW[160 * 20]; // scaled panel rows
  __shared__ float stj[152];
  __shared__ float sAmu[304];
  __shared__ float sKp[304];
  __shared__ float red[8];

  const int j = blockIdx.x >> 4;
  const int d = blockIdx.x & 15;
  if (j == 0)      build_impl<0>(d, ts, log_tau, ws, sS, sU, sW, stj, sAmu, sKp, red);
  else if (j == 1) build_impl<1>(d, ts, log_tau, ws, sS, sU, sW, stj, sAmu, sKp, red);
  else             build_impl<2>(d, ts, log_tau, ws, sS, sU, sW, stj, sAmu, sKp, red);
}

// ---------------------------------------------------------------------------
// Kernel B (MFMA), 64-row blocks: out[b, p] = sum_k Z'[b,k] * LB[p,k].
// Each wave holds A-fragments for ALL 64 rows (4 row-tiles) and owns a
// DISJOINT p-tile range -> each LB fragment load feeds 4 MFMAs (was 1),
// LB L2 traffic 1x per block (was 4x duplicated across waves), and block
// count halves. Z' tile (64 x KS bf16) staged in LDS.
// ---------------------------------------------------------------------------
template <int M, int MP, int KS, int KT, int TOFF, int OOFF, int LBOFF>
__device__ __forceinline__ void apply_impl(const float* __restrict__ z,
                                           const unsigned* __restrict__ wsu,
                                           float* __restrict__ out,
                                           char* smem, int blk)
{
  constexpr int PT = MP / 16;           // p-tiles
  constexpr int CK = KS / 8;            // 8-col chunks per Z row
  const int d   = blk & 15;
  const int bs0 = (blk >> 4) * 64;      // 64-row group (blk>>4 in 0..31)
  const int tid = threadIdx.x;
  const int lane = tid & 63;
  const int wv   = tid >> 6;            // 4 waves, each owns a p-tile range

  unsigned short* Zs = (unsigned short*)smem;   // 64 x KS bf16

  // stage Z' tile (bf16): row r, cols k -> z[row][TOFF+k] | zf | zl | 0
  for (int idx = tid; idx < 64 * CK; idx += 256) {
    const int r = idx / CK;             // constexpr CK -> magic mul
    const int k0 = (idx - r * CK) * 8;
    const float* zr = z + (size_t)((bs0 + r) * 16 + d) * 302;
    us8_t v;
    if (k0 + 8 <= M) {
#pragma unroll
      for (int t = 0; t < 4; ++t) {
        const float2 f = *(const float2*)(zr + TOFF + k0 + 2 * t);
        v[2 * t]     = f2bf(f.x);
        v[2 * t + 1] = f2bf(f.y);
      }
    } else {
#pragma unroll
      for (int e = 0; e < 8; ++e) {
        const int k = k0 + e;
        float f;
        if (k < M)           f = zr[TOFF + k];
        else if (k == M)     f = zr[0];
        else if (k == M + 1) f = zr[1];
        else                 f = 0.0f;
        v[e] = f2bf(f);
      }
    }
    *(us8_t*)&Zs[r * KS + k0] = v;
  }

  // zf / zl pass-through columns (exact fp32), 64 rows x 2
  if (tid < 128) {
    const int r = tid >> 1;
    const int which = tid & 1;
    const float* zr = z + (size_t)((bs0 + r) * 16 + d) * 302;
    out[(size_t)((bs0 + r) * 16 + d) * 306 + OOFF + (which ? (M + 1) : 0)] = zr[which];
  }
  __syncthreads();

  // A fragments for all 4 row-tiles: rt*16 + (lane&15), koff = (lane>>4)*8
  bf8_t afr[4][KT];
  {
    const int arow = lane & 15;
    const int koff = (lane >> 4) * 8;
#pragma unroll
    for (int rt = 0; rt < 4; ++rt)
#pragma unroll
      for (int kt = 0; kt < KT; ++kt)
        afr[rt][kt] = *(const bf8_t*)&Zs[(rt * 16 + arow) * KS + kt * 32 + koff];
  }

  const unsigned short* LBd = (const unsigned short*)(wsu + LBOFF + d * (MP * (KS / 2)));
  const int pt0 = (PT * wv) >> 2;       // disjoint p-tile range per wave
  const int pt1 = (PT * (wv + 1)) >> 2;
  for (int pt = pt0; pt < pt1; ++pt) {
    const int p = pt * 16 + (lane & 15);
    const unsigned short* bb = &LBd[p * KS + (lane >> 4) * 8];
    // hoist all KT B-fragments for this p-tile (each feeds 4 MFMAs)
    bf8_t bfr[KT];
#pragma unroll
    for (int kt = 0; kt < KT; ++kt)
      bfr[kt] = *(const bf8_t*)&bb[kt * 32];   // 16B global load (L2)
#pragma unroll
    for (int rt = 0; rt < 4; ++rt) {
      f32x4 acc = {0.0f, 0.0f, 0.0f, 0.0f};
#pragma unroll
      for (int kt = 0; kt < KT; ++kt)
        acc = __builtin_amdgcn_mfma_f32_16x16x32_bf16(afr[rt][kt], bfr[kt], acc, 0, 0, 0);
      if (p < M) {
        const int rbase = bs0 + rt * 16 + (lane >> 4) * 4;
#pragma unroll
        for (int e = 0; e < 4; ++e)
          out[(size_t)((rbase + e) * 16 + d) * 306 + OOFF + 1 + p] = acc[e];
      }
    }
  }
}

__global__ __launch_bounds__(256) void apply_kernel(const float* __restrict__ z,
                                                    const unsigned* __restrict__ wsu,
                                                    float* __restrict__ out,
                                                    const float* __restrict__ part,
                                                    const float* __restrict__ sldj,
                                                    int last)
{
  __shared__ __attribute__((aligned(16))) char smem[21504]; // 64*168*2
  const int bid = blockIdx.x;
  if (bid == 1535 && threadIdx.x == 0) {
    // fused finalize: ldj = sldj_in + sum of 48 build partials
    float s = sldj[0];
#pragma unroll
    for (int i = 0; i < 48; ++i) s += part[i];
    out[last] = s;
  }
  if (bid < 512)       apply_impl<150, 160, 168, 5, 152, 154, LB2_OFF>(z, wsu, out, smem, bid);
  else if (bid < 1024) apply_impl<100, 112, 136, 4,  52,  52, LB1_OFF>(z, wsu, out, smem, bid - 512);
  else                 apply_impl< 50,  64,  72, 2,   2,   0, LB0_OFF>(z, wsu, out, smem, bid - 1024);
}

extern "C" void kernel_launch(void* const* d_in, const int* in_sizes, int n_in,
                              void* d_out, int out_size, void* d_ws, size_t ws_size,
                              hipStream_t stream)
{
  const float* z       = (const float*)d_in[0];  // (16,128,16,302)
  const float* ts      = (const float*)d_in[1];  // (3,50) flat
  const float* log_tau = (const float*)d_in[2];  // (16,)
  const float* sldj    = (const float*)d_in[3];  // scalar
  float* out = (float*)d_out;                    // 16*128*16*306 + 1
  float* ws  = (float*)d_ws;

  hipLaunchKernelGGL(build_kernel, dim3(48), dim3(BNT), 0, stream, ts, log_tau, ws);
  hipLaunchKernelGGL(apply_kernel, dim3(1536), dim3(256), 0, stream,
                     z, (const unsigned*)ws, out,
                     ws + PART_OFF, sldj, out_size - 1);
}